// Round 9
// baseline (133.815 us; speedup 1.0000x reference)
//
#include <hip/hip_runtime.h>
#include <cstdint>
#include <cstddef>

typedef __attribute__((ext_vector_type(8))) short short8;
typedef __attribute__((ext_vector_type(8))) unsigned short ushort8;
typedef __attribute__((ext_vector_type(4))) float f32x4;

#define AS1Q const __attribute__((address_space(1)))
#define AS3Q __attribute__((address_space(3)))

constexpr int T_N = 60, IN_N = 520, MOE_RAW_N = 512, MOE_IN_N = 992;
constexpr int HID_N = 752, E_N = 8;
constexpr int K2_N = 6016;            // 8*752
constexpr int KA_N = 1024;            // padded Xm row length (992 -> 1024)
constexpr int SPLITK = 20;
constexpr int PN = 768;               // P row pitch

static __device__ __forceinline__ unsigned short f2bf(float f) {
  unsigned int u = __float_as_uint(f);
  return (unsigned short)((u + 0x7fffu + ((u >> 16) & 1u)) >> 16);   // RNE
}
static __device__ __forceinline__ float sigf(float x) {
  return __fdividef(1.f, 1.f + __expf(-x));
}
static __device__ __forceinline__ float tanh_fast(float x) {
  return 2.f * __fdividef(1.f, 1.f + __expf(-2.f * x)) - 1.f;
}

// DPP row-rotate by R within the 16-lane row (pure VALU — no LDS pipe).
template<int R>
static __device__ __forceinline__ float rotf(float v) {
  return __int_as_float(__builtin_amdgcn_update_dpp(
      0, __float_as_int(v), 0x120 | R, 0xF, 0xF, true));
}
static __device__ __forceinline__ void rot8(float (&d)[8], float v) {
  d[0] = v;
  d[1] = rotf<1>(v); d[2] = rotf<2>(v); d[3] = rotf<3>(v);
  d[4] = rotf<4>(v); d[5] = rotf<5>(v); d[6] = rotf<6>(v); d[7] = rotf<7>(v);
}

// ---------------------------------------------------------------------------
// FUSED: GRU (blocks 0..15) + expert-separated layer-1 GEMM (blocks 16..111).
// GEMM1 A-tiles are reg-staged DIRECTLY from X (xm_prep eliminated):
//   Xm(b,k) = X[b,59,k]                       (k < 512)
//           = X[b,(k-512)/8, 512+(k-512)%8]   (512 <= k < 992)  -- 8-contig!
//           = 0                               (k >= 992, pad to 1024)
// Y1[e][b][h] = Xm_b @ w1_e needs no Omega -> runs concurrently with the GRU.
// GRU body = round-6/8 validated version.
// ---------------------------------------------------------------------------
__global__ __launch_bounds__(256, 1)
void fused_gru_gemm1(const float* __restrict__ X,
                     const float* __restrict__ Wih0, const float* __restrict__ Whh0,
                     const float* __restrict__ bih0, const float* __restrict__ bhh0,
                     const float* __restrict__ Wih1, const float* __restrict__ Whh1,
                     const float* __restrict__ bih1, const float* __restrict__ bhh1,
                     const float* __restrict__ w1,
                     float* __restrict__ Y1, float* __restrict__ Omega)
{
  __shared__ union SM {
    struct { unsigned short Al[2][256][64]; unsigned short Bl[2][64][64]; } g; // 80 KB
    float xl[T_N][256];                                                        // 60 KB
  } sm;

  const int tid  = threadIdx.x;
  const int lane = tid & 63;
  const int wave = tid >> 6;

  if (blockIdx.x < 16) {
    // ================= GRU branch: 16 samples per block =================
    const int j = tid & 7;
    const int b = blockIdx.x * 16 + (tid >> 4);

    const float* xsrc = X + (size_t)b * (T_N * IN_N) + MOE_RAW_N + j;
#pragma unroll
    for (int t = 0; t < T_N; ++t) {
      __builtin_amdgcn_global_load_lds((AS1Q unsigned int*)(xsrc + t * IN_N),
                                       (AS3Q unsigned int*)&sm.xl[t][wave * 64], 4, 0, 0);
    }

    const int got = __builtin_amdgcn_update_dpp(0, j, 0x121, 0xF, 0xF, true);
    const bool plus = (got == ((j + 1) & 7));

    float wi0r[8], wi0z[8], wi0n[8], wh0r[8], wh0z[8], wh0n[8];
    float wi1r[8], wi1z[8], wi1n[8], wh1r[8], wh1z[8], wh1n[8];
#pragma unroll
    for (int r = 0; r < 8; ++r) {
      const int i = plus ? ((j + r) & 7) : ((j - r) & 7);
      wi0r[r] = Wih0[j * 8 + i]; wi0z[r] = Wih0[(8 + j) * 8 + i]; wi0n[r] = Wih0[(16 + j) * 8 + i];
      wh0r[r] = Whh0[j * 8 + i]; wh0z[r] = Whh0[(8 + j) * 8 + i]; wh0n[r] = Whh0[(16 + j) * 8 + i];
      wi1r[r] = Wih1[j * 8 + i]; wi1z[r] = Wih1[(8 + j) * 8 + i]; wi1n[r] = Wih1[(16 + j) * 8 + i];
      wh1r[r] = Whh1[j * 8 + i]; wh1z[r] = Whh1[(8 + j) * 8 + i]; wh1n[r] = Whh1[(16 + j) * 8 + i];
    }
    const float br0 = bih0[j] + bhh0[j], bz0 = bih0[8 + j] + bhh0[8 + j];
    const float bin0 = bih0[16 + j],     bhn0 = bhh0[16 + j];
    const float br1 = bih1[j] + bhh1[j], bz1 = bih1[8 + j] + bhh1[8 + j];
    const float bin1 = bih1[16 + j],     bhn1 = bhh1[16 + j];

    __syncthreads();   // xl ready

    float h1 = 0.f, h2 = 0.f;
    float xcur = sm.xl[0][tid];

#pragma unroll 1
    for (int t = 0; t <= T_N; ++t) {   // 61 iterations (software pipeline)
      const float xnext = sm.xl[(t + 1 < T_N) ? t + 1 : T_N - 1][tid];

      float rx[8];  rot8(rx, xcur);
      float rh1[8]; rot8(rh1, h1);     // feeds BOTH chains
      float rh2[8]; rot8(rh2, h2);

      // chain A: layer 0, step t
      float grA = br0, gzA = bz0, gnA = bin0, hnA = bhn0;
      float grB = 0.f, gzB = 0.f, gnB = 0.f, hnB = 0.f;
#pragma unroll
      for (int r = 0; r < 4; ++r) {
        grA += wi0r[r] * rx[r];     gzA += wi0z[r] * rx[r];     gnA += wi0n[r] * rx[r];
        grA += wh0r[r] * rh1[r];    gzA += wh0z[r] * rh1[r];    hnA += wh0n[r] * rh1[r];
        grB += wi0r[4+r] * rx[4+r]; gzB += wi0z[4+r] * rx[4+r]; gnB += wi0n[4+r] * rx[4+r];
        grB += wh0r[4+r] * rh1[4+r];gzB += wh0z[4+r] * rh1[4+r];hnB += wh0n[4+r] * rh1[4+r];
      }
      float h1n;
      {
        const float r0 = sigf(grA + grB), z0 = sigf(gzA + gzB);
        const float n0 = tanh_fast((gnA + gnB) + r0 * (hnA + hnB));
        h1n = (1.f - z0) * n0 + z0 * h1;
      }

      // chain B: layer 1, step t-1
      float grA1 = br1, gzA1 = bz1, gnA1 = bin1, hnA1 = bhn1;
      float grB1 = 0.f, gzB1 = 0.f, gnB1 = 0.f, hnB1 = 0.f;
#pragma unroll
      for (int r = 0; r < 4; ++r) {
        grA1 += wi1r[r] * rh1[r];     gzA1 += wi1z[r] * rh1[r];     gnA1 += wi1n[r] * rh1[r];
        grA1 += wh1r[r] * rh2[r];     gzA1 += wh1z[r] * rh2[r];     hnA1 += wh1n[r] * rh2[r];
        grB1 += wi1r[4+r] * rh1[4+r]; gzB1 += wi1z[4+r] * rh1[4+r]; gnB1 += wi1n[4+r] * rh1[4+r];
        grB1 += wh1r[4+r] * rh2[4+r]; gzB1 += wh1z[4+r] * rh2[4+r]; hnB1 += wh1n[4+r] * rh2[4+r];
      }
      float h2n;
      {
        const float r1 = sigf(grA1 + grB1), z1 = sigf(gzA1 + gzB1);
        const float n1 = tanh_fast((gnA1 + gnB1) + r1 * (hnA1 + hnB1));
        h2n = (1.f - z1) * n1 + z1 * h2;
      }

      h1 = h1n;
      h2 = (t == 0) ? 0.f : h2n;   // t=0 warm-up discard
      xcur = xnext;
    }

    // softmax over the 8 hidden units via rotations
    float rv[8]; rot8(rv, h2);
    float m = rv[0];
#pragma unroll
    for (int r = 1; r < 8; ++r) m = fmaxf(m, rv[r]);
    const float ej = __expf(h2 - m);
    float re[8]; rot8(re, ej);
    float sden = 0.f;
#pragma unroll
    for (int r = 0; r < 8; ++r) sden += re[r];
    if (!(tid & 8)) Omega[b * 8 + j] = __fdividef(ej, sden);
    return;
  }

  // ================= GEMM branch: Y1[e] = Xm @ w1_e (full K) =================
  const int bid = blockIdx.x - 16;           // 0..95
  const int e   = bid & 7;
  const int nt  = bid >> 3;                  // 0..11
  const int n0  = nt * 64;

  const int r15 = lane & 15, hi4 = lane >> 4, r7 = lane & 7;
  const int g = lane >> 3, c = lane & 7;
  const int sw = ((c ^ g) << 3);             // write chunk offset (elements)

  const int bn = lane;
  const int kq = wave;
  const bool nvalid = (n0 + bn) < HID_N;
  const float* Bbase = w1 + ((size_t)e * MOE_IN_N + kq * 16) * HID_N + (n0 + bn);

  f32x4 acc[4][4];
  const f32x4 zero4 = {0.f, 0.f, 0.f, 0.f};
#pragma unroll
  for (int mi = 0; mi < 4; ++mi)
#pragma unroll
    for (int ni = 0; ni < 4; ++ni) acc[mi][ni] = zero4;

  auto stage = [&](int bufi, int kt) {
    // A: reg-stage 8 rows x 8 k directly from X, swizzled ds_write_b128
    const int k0 = kt * 64 + c * 8;
#pragma unroll
    for (int it = 0; it < 8; ++it) {
      const int row = wave * 64 + g + it * 8;           // sample b
      f32x4 v0 = zero4, v1 = zero4;
      if (k0 < MOE_RAW_N) {
        const float* p = X + (size_t)row * (T_N * IN_N) + (T_N - 1) * IN_N + k0;
        v0 = *(const f32x4*)p; v1 = *(const f32x4*)(p + 4);
      } else if (k0 < MOE_IN_N) {
        const int tt = (k0 - MOE_RAW_N) >> 3;
        const float* p = X + (size_t)row * (T_N * IN_N) + tt * IN_N + MOE_RAW_N;
        v0 = *(const f32x4*)p; v1 = *(const f32x4*)(p + 4);
      }
      ushort8 pk;
#pragma unroll
      for (int jj = 0; jj < 4; ++jj) { pk[jj] = f2bf(v0[jj]); pk[4 + jj] = f2bf(v1[jj]); }
      *(ushort8*)&sm.g.Al[bufi][row][sw] = pk;
    }
    // B: reg-stage fp32->bf16 transposed, swizzled
    const int kbase = kt * 64 + kq * 16;
    const float* gb = Bbase + (size_t)kt * 64 * HID_N;
    float v[16];
#pragma unroll
    for (int jj = 0; jj < 16; ++jj)
      v[jj] = (nvalid && (kbase + jj) < MOE_IN_N) ? gb[(size_t)jj * HID_N] : 0.f;
    ushort8 p0, p1;
#pragma unroll
    for (int jj = 0; jj < 8; ++jj) { p0[jj] = f2bf(v[jj]); p1[jj] = f2bf(v[jj + 8]); }
    const int sl0 = ((kq * 2) ^ (bn & 7)) * 8;
    const int sl1 = ((kq * 2 + 1) ^ (bn & 7)) * 8;
    *(ushort8*)&sm.g.Bl[bufi][bn][sl0] = p0;
    *(ushort8*)&sm.g.Bl[bufi][bn][sl1] = p1;
  };

  auto compute = [&](int bufi) {
#pragma unroll
    for (int ki = 0; ki < 2; ++ki) {
      const int ch = ((ki * 4 + hi4) ^ r7) * 8;
      short8 af[4], bfv[4];
#pragma unroll
      for (int mi = 0; mi < 4; ++mi)
        af[mi] = *(const short8*)&sm.g.Al[bufi][wave * 64 + mi * 16 + r15][ch];
#pragma unroll
      for (int ni = 0; ni < 4; ++ni)
        bfv[ni] = *(const short8*)&sm.g.Bl[bufi][ni * 16 + r15][ch];
#pragma unroll
      for (int mi = 0; mi < 4; ++mi)
#pragma unroll
        for (int ni = 0; ni < 4; ++ni)
          acc[mi][ni] = __builtin_amdgcn_mfma_f32_16x16x32_bf16(af[mi], bfv[ni], acc[mi][ni], 0, 0, 0);
    }
  };

  stage(0, 0);
  __syncthreads();
  int buf = 0;
  for (int kt = 0; kt < 16; ++kt) {
    if (kt + 1 < 16) stage(buf ^ 1, kt + 1);
    compute(buf);
    __syncthreads();
    buf ^= 1;
  }

  float* Pp = Y1 + ((size_t)e * 256) * PN + n0;
#pragma unroll
  for (int mi = 0; mi < 4; ++mi) {
    const int row = wave * 64 + mi * 16 + hi4 * 4;
#pragma unroll
    for (int ni = 0; ni < 4; ++ni) {
#pragma unroll
      for (int rq = 0; rq < 4; ++rq)
        Pp[(size_t)(row + rq) * PN + ni * 16 + r15] = acc[mi][ni][rq];
    }
  }
}

// ---------------------------------------------------------------------------
// reduce1: zero P (for gemm2 atomics), then
// a1 = elu( Sum_e Omega_e*Y1[e] + Omega@b1 ) -> swizzled bf16 xt2.
// ---------------------------------------------------------------------------
__global__ __launch_bounds__(256)
void reduce1_mix(const float* __restrict__ Y1, const float* __restrict__ Omega,
                 const float* __restrict__ bias, unsigned short* __restrict__ xnext,
                 float* __restrict__ P)
{
  const int n = blockIdx.x * 256 + threadIdx.x;   // 0..767
  const int b = blockIdx.y;
  P[(size_t)b * PN + n] = 0.f;                    // zero for gemm2 atomics
  if (n >= HID_N) return;
  float om[8];
#pragma unroll
  for (int e = 0; e < 8; ++e) om[e] = Omega[b * 8 + e];
  float acc = 0.f, bs = 0.f;
#pragma unroll
  for (int e = 0; e < 8; ++e) {
    acc += om[e] * Y1[((size_t)e * 256 + b) * PN + n];
    bs  += om[e] * bias[(size_t)e * HID_N + n];
  }
  const float y = acc + bs;
  const float a = (y > 0.f) ? y : expm1f(y);      // ELU
  const int swz = (b & 7) << 3;
  unsigned short* row = xnext + (size_t)b * K2_N;
#pragma unroll
  for (int e = 0; e < 8; ++e)
    row[(e * HID_N + n) ^ swz] = f2bf(om[e] * a);
}

// ---------------------------------------------------------------------------
// Split-K GEMM, atomic reduction: P[b][n] += A_slice @ B_slice.
// P must be pre-zeroed (done by the preceding reduce kernel).
// ---------------------------------------------------------------------------
__global__ __launch_bounds__(256)
void gemm_splitk_atomic(const unsigned short* __restrict__ A,
                        const float* __restrict__ Bw,
                        float* __restrict__ P,
                        int K, int N)
{
  __shared__ unsigned short Al[2][256][64];
  __shared__ unsigned short Bl[2][64][64];

  const int tid = threadIdx.x;
  const int lane = tid & 63;
  const int wave = tid >> 6;
  const int nt = blockIdx.x, sp = blockIdx.y;
  const int n0 = nt * 64;
  const int KT = K >> 6;
  const int kt0 = (KT * sp) / SPLITK;
  const int kt1 = (KT * (sp + 1)) / SPLITK;

  const int r15 = lane & 15, hi4 = lane >> 4, r7 = lane & 7;

  const unsigned short* Abase = A + (size_t)(wave * 64 + (lane >> 3)) * K + (lane & 7) * 8;
  const int bn = lane;
  const int kq = wave;
  const bool nvalid = (n0 + bn) < N;
  const float* Bbase = Bw + (size_t)(kq * 16) * N + (n0 + bn);

  f32x4 acc[4][4];
  const f32x4 zero4 = {0.f, 0.f, 0.f, 0.f};
#pragma unroll
  for (int mi = 0; mi < 4; ++mi)
#pragma unroll
    for (int ni = 0; ni < 4; ++ni) acc[mi][ni] = zero4;

  auto stage = [&](int bufi, int kt) {
    const unsigned short* ga = Abase + kt * 64;
#pragma unroll
    for (int it = 0; it < 8; ++it) {
      __builtin_amdgcn_global_load_lds(
          (AS1Q unsigned int*)(ga + (size_t)it * 8 * K),
          (AS3Q unsigned int*)&Al[bufi][wave * 64 + it * 8][0],
          16, 0, 0);
    }
    const float* gb = Bbase + (size_t)kt * 64 * N;
    float v[16];
#pragma unroll
    for (int jj = 0; jj < 16; ++jj) v[jj] = nvalid ? gb[(size_t)jj * N] : 0.f;
    ushort8 p0, p1;
#pragma unroll
    for (int jj = 0; jj < 8; ++jj) { p0[jj] = f2bf(v[jj]); p1[jj] = f2bf(v[jj + 8]); }
    const int sl0 = ((kq * 2) ^ (bn & 7)) * 8;
    const int sl1 = ((kq * 2 + 1) ^ (bn & 7)) * 8;
    *(ushort8*)&Bl[bufi][bn][sl0] = p0;
    *(ushort8*)&Bl[bufi][bn][sl1] = p1;
  };

  auto compute = [&](int bufi) {
#pragma unroll
    for (int ki = 0; ki < 2; ++ki) {
      const int ch = ((ki * 4 + hi4) ^ r7) * 8;
      short8 af[4], bfv[4];
#pragma unroll
      for (int mi = 0; mi < 4; ++mi)
        af[mi] = *(const short8*)&Al[bufi][wave * 64 + mi * 16 + r15][ch];
#pragma unroll
      for (int ni = 0; ni < 4; ++ni)
        bfv[ni] = *(const short8*)&Bl[bufi][ni * 16 + r15][ch];
#pragma unroll
      for (int mi = 0; mi < 4; ++mi)
#pragma unroll
        for (int ni = 0; ni < 4; ++ni)
          acc[mi][ni] = __builtin_amdgcn_mfma_f32_16x16x32_bf16(af[mi], bfv[ni], acc[mi][ni], 0, 0, 0);
    }
  };

  stage(0, kt0);
  __syncthreads();
  int buf = 0;
  for (int kt = kt0; kt < kt1; ++kt) {
    if (kt + 1 < kt1) stage(buf ^ 1, kt + 1);
    compute(buf);
    __syncthreads();
    buf ^= 1;
  }

  float* Pp = P + n0;
#pragma unroll
  for (int mi = 0; mi < 4; ++mi) {
    const int row = wave * 64 + mi * 16 + hi4 * 4;
#pragma unroll
    for (int ni = 0; ni < 4; ++ni) {
#pragma unroll
      for (int rq = 0; rq < 4; ++rq)
        atomicAdd(&Pp[(size_t)(row + rq) * PN + ni * 16 + r15], acc[mi][ni][rq]);
    }
  }
}

// ---------------------------------------------------------------------------
// reduce_p: y = P[b][n] + Omega@bias; optional re-zero of P (for next gemm);
// then ELU+mix -> xnext, or final fp32 -> Yout.
// ---------------------------------------------------------------------------
__global__ __launch_bounds__(256)
void reduce_p(float* __restrict__ P, const float* __restrict__ Omega,
              const float* __restrict__ bias, unsigned short* __restrict__ xnext,
              float* __restrict__ Yout, int N, int zeroP)
{
  const int n = blockIdx.x * 256 + threadIdx.x;
  const int b = blockIdx.y;
  float v = 0.f;
  if (n < PN) {
    v = P[(size_t)b * PN + n];
    if (zeroP) P[(size_t)b * PN + n] = 0.f;
  }
  if (n >= N) return;
  float om[8];
#pragma unroll
  for (int e = 0; e < 8; ++e) om[e] = Omega[b * 8 + e];
  float bs = 0.f;
#pragma unroll
  for (int e = 0; e < 8; ++e) bs += om[e] * bias[(size_t)e * N + n];
  const float y = v + bs;
  if (Yout) { Yout[(size_t)b * N + n] = y; return; }
  const float a = (y > 0.f) ? y : expm1f(y);      // ELU
  const int swz = (b & 7) << 3;
  unsigned short* row = xnext + (size_t)b * K2_N;
#pragma unroll
  for (int e = 0; e < 8; ++e)
    row[(e * HID_N + n) ^ swz] = f2bf(om[e] * a);
}

// ---------------------------------------------------------------------------
extern "C" void kernel_launch(void* const* d_in, const int* in_sizes, int n_in,
                              void* d_out, int out_size, void* d_ws, size_t ws_size,
                              hipStream_t stream) {
  const float* X    = (const float*)d_in[0];
  const float* Wih0 = (const float*)d_in[1];
  const float* Whh0 = (const float*)d_in[2];
  const float* bih0 = (const float*)d_in[3];
  const float* bhh0 = (const float*)d_in[4];
  const float* Wih1 = (const float*)d_in[5];
  const float* Whh1 = (const float*)d_in[6];
  const float* bih1 = (const float*)d_in[7];
  const float* bhh1 = (const float*)d_in[8];
  const float* w1   = (const float*)d_in[9];
  const float* b1   = (const float*)d_in[10];
  const float* w2   = (const float*)d_in[11];
  const float* b2   = (const float*)d_in[12];
  const float* w3   = (const float*)d_in[13];
  const float* b3   = (const float*)d_in[14];

  char* ws = (char*)d_ws;
  float* Omega        = (float*)ws;                       // 8 KB
  unsigned short* xt2 = (unsigned short*)(ws + 8192);     // 3,080,192
  unsigned short* xt3 = (unsigned short*)(ws + 3088384);  // 3,080,192
  float* Y1           = (float*)(ws + 6168576);           // 8*256*768*4 = 6,291,456
  float* P            = (float*)(ws + 12460032);          // 256*768*4  =   786,432

  // GRU (16 blocks) + full-K expert GEMM1 staged from X (96 blocks)
  fused_gru_gemm1<<<112, 256, 0, stream>>>(X, Wih0, Whh0, bih0, bhh0,
                                           Wih1, Whh1, bih1, bhh1,
                                           w1, Y1, Omega);

  // fold Omega + bias + ELU -> xt2 ; zero P for gemm2 atomics
  reduce1_mix<<<dim3(3, 256), 256, 0, stream>>>(Y1, Omega, b1, xt2, P);

  // layer 2: 256 x 6016 @ 6016 x 752  (atomic split-K into P)
  gemm_splitk_atomic<<<dim3(12, SPLITK), 256, 0, stream>>>(xt2, w2, P, K2_N, HID_N);
  reduce_p<<<dim3(3, 256), 256, 0, stream>>>(P, Omega, b2, xt3, nullptr, HID_N, 1);

  // layer 3: 256 x 6016 @ 6016 x 512  (atomic split-K into P)
  gemm_splitk_atomic<<<dim3(8, SPLITK), 256, 0, stream>>>(xt3, w3, P, K2_N, 512);
  reduce_p<<<dim3(2, 256), 256, 0, stream>>>(P, Omega, b3, nullptr, (float*)d_out, 512, 0);
}

// Round 10
// 92.728 us; speedup vs baseline: 1.4431x; 1.4431x over previous
//
#include <hip/hip_runtime.h>
#include <cstdint>
#include <cstddef>

typedef __attribute__((ext_vector_type(8))) short short8;
typedef __attribute__((ext_vector_type(8))) unsigned short ushort8;
typedef __attribute__((ext_vector_type(4))) float f32x4;

#define AS1Q const __attribute__((address_space(1)))
#define AS3Q __attribute__((address_space(3)))

constexpr int T_N = 60, IN_N = 520, MOE_RAW_N = 512, MOE_IN_N = 992;
constexpr int HID_N = 752, E_N = 8;
constexpr int K2_N = 6016;            // 8*752
constexpr int KA_N = 1024;            // padded Xm row length (992 -> 1024)
constexpr int SPLITK = 20;
constexpr int PN = 768;               // P row pitch

static __device__ __forceinline__ unsigned short f2bf(float f) {
  unsigned int u = __float_as_uint(f);
  return (unsigned short)((u + 0x7fffu + ((u >> 16) & 1u)) >> 16);   // RNE
}
static __device__ __forceinline__ float sigf(float x) {
  return __fdividef(1.f, 1.f + __expf(-x));
}
static __device__ __forceinline__ float tanh_fast(float x) {
  return 2.f * __fdividef(1.f, 1.f + __expf(-2.f * x)) - 1.f;
}

// DPP row-rotate by R within the 16-lane row (pure VALU — no LDS pipe).
template<int R>
static __device__ __forceinline__ float rotf(float v) {
  return __int_as_float(__builtin_amdgcn_update_dpp(
      0, __float_as_int(v), 0x120 | R, 0xF, 0xF, true));
}
static __device__ __forceinline__ void rot8(float (&d)[8], float v) {
  d[0] = v;
  d[1] = rotf<1>(v); d[2] = rotf<2>(v); d[3] = rotf<3>(v);
  d[4] = rotf<4>(v); d[5] = rotf<5>(v); d[6] = rotf<6>(v); d[7] = rotf<7>(v);
}

// ---------------------------------------------------------------------------
// xm_prep: Xm_bf16[b][ (i ^ (b&7)<<3) ] = bf16(Xm[b,i]), rows padded to 1024
// with zeros. Omega-FREE. (R8-measured configuration — R9's direct-X staging
// regressed 2.5x: 16-tile serial chains + ds_write bank conflicts.)
// ---------------------------------------------------------------------------
__global__ __launch_bounds__(256)
void xm_prep(const float* __restrict__ X, unsigned short* __restrict__ XmBf)
{
  const int i = blockIdx.x * 256 + threadIdx.x;   // grid.x=4 -> 0..1023
  const int b = blockIdx.y;
  const float* Xb = X + (size_t)b * (T_N * IN_N);
  float v = 0.f;
  if (i < MOE_RAW_N) {
    v = Xb[(T_N - 1) * IN_N + i];
  } else if (i < MOE_IN_N) {
    const int q = i - MOE_RAW_N;
    v = Xb[(q >> 3) * IN_N + MOE_RAW_N + (q & 7)];
  }
  XmBf[(size_t)b * KA_N + (i ^ ((b & 7) << 3))] = f2bf(v);
}

// ---------------------------------------------------------------------------
// FUSED: GRU (blocks 0..15) + expert-separated layer-1 GEMM (blocks 16..207).
// Y1[sp][e][b][h] = Xm_b @ w1_e (no Omega needed) runs CONCURRENTLY with the
// latency-bound GRU. R8-measured configuration: 192 GEMM blocks x 8 K-tiles,
// A staged via global_load_lds from L2-hot XmBf.
// ---------------------------------------------------------------------------
__global__ __launch_bounds__(256, 1)
void fused_gru_gemm1(const float* __restrict__ X,
                     const float* __restrict__ Wih0, const float* __restrict__ Whh0,
                     const float* __restrict__ bih0, const float* __restrict__ bhh0,
                     const float* __restrict__ Wih1, const float* __restrict__ Whh1,
                     const float* __restrict__ bih1, const float* __restrict__ bhh1,
                     const unsigned short* __restrict__ XmBf,
                     const float* __restrict__ w1,
                     float* __restrict__ Y1, float* __restrict__ Omega)
{
  __shared__ union SM {
    struct { unsigned short Al[2][256][64]; unsigned short Bl[2][64][64]; } g; // 80 KB
    float xl[T_N][256];                                                        // 60 KB
  } sm;

  const int tid  = threadIdx.x;
  const int lane = tid & 63;
  const int wave = tid >> 6;

  if (blockIdx.x < 16) {
    // ================= GRU branch: 16 samples per block =================
    const int j = tid & 7;
    const int b = blockIdx.x * 16 + (tid >> 4);

    const float* xsrc = X + (size_t)b * (T_N * IN_N) + MOE_RAW_N + j;
#pragma unroll
    for (int t = 0; t < T_N; ++t) {
      __builtin_amdgcn_global_load_lds((AS1Q unsigned int*)(xsrc + t * IN_N),
                                       (AS3Q unsigned int*)&sm.xl[t][wave * 64], 4, 0, 0);
    }

    const int got = __builtin_amdgcn_update_dpp(0, j, 0x121, 0xF, 0xF, true);
    const bool plus = (got == ((j + 1) & 7));

    float wi0r[8], wi0z[8], wi0n[8], wh0r[8], wh0z[8], wh0n[8];
    float wi1r[8], wi1z[8], wi1n[8], wh1r[8], wh1z[8], wh1n[8];
#pragma unroll
    for (int r = 0; r < 8; ++r) {
      const int i = plus ? ((j + r) & 7) : ((j - r) & 7);
      wi0r[r] = Wih0[j * 8 + i]; wi0z[r] = Wih0[(8 + j) * 8 + i]; wi0n[r] = Wih0[(16 + j) * 8 + i];
      wh0r[r] = Whh0[j * 8 + i]; wh0z[r] = Whh0[(8 + j) * 8 + i]; wh0n[r] = Whh0[(16 + j) * 8 + i];
      wi1r[r] = Wih1[j * 8 + i]; wi1z[r] = Wih1[(8 + j) * 8 + i]; wi1n[r] = Wih1[(16 + j) * 8 + i];
      wh1r[r] = Whh1[j * 8 + i]; wh1z[r] = Whh1[(8 + j) * 8 + i]; wh1n[r] = Whh1[(16 + j) * 8 + i];
    }
    const float br0 = bih0[j] + bhh0[j], bz0 = bih0[8 + j] + bhh0[8 + j];
    const float bin0 = bih0[16 + j],     bhn0 = bhh0[16 + j];
    const float br1 = bih1[j] + bhh1[j], bz1 = bih1[8 + j] + bhh1[8 + j];
    const float bin1 = bih1[16 + j],     bhn1 = bhh1[16 + j];

    __syncthreads();   // xl ready

    float h1 = 0.f, h2 = 0.f;
    float xcur = sm.xl[0][tid];

#pragma unroll 1
    for (int t = 0; t <= T_N; ++t) {   // 61 iterations (software pipeline)
      const float xnext = sm.xl[(t + 1 < T_N) ? t + 1 : T_N - 1][tid];

      float rx[8];  rot8(rx, xcur);
      float rh1[8]; rot8(rh1, h1);     // feeds BOTH chains
      float rh2[8]; rot8(rh2, h2);

      // chain A: layer 0, step t
      float grA = br0, gzA = bz0, gnA = bin0, hnA = bhn0;
      float grB = 0.f, gzB = 0.f, gnB = 0.f, hnB = 0.f;
#pragma unroll
      for (int r = 0; r < 4; ++r) {
        grA += wi0r[r] * rx[r];     gzA += wi0z[r] * rx[r];     gnA += wi0n[r] * rx[r];
        grA += wh0r[r] * rh1[r];    gzA += wh0z[r] * rh1[r];    hnA += wh0n[r] * rh1[r];
        grB += wi0r[4+r] * rx[4+r]; gzB += wi0z[4+r] * rx[4+r]; gnB += wi0n[4+r] * rx[4+r];
        grB += wh0r[4+r] * rh1[4+r];gzB += wh0z[4+r] * rh1[4+r];hnB += wh0n[4+r] * rh1[4+r];
      }
      float h1n;
      {
        const float r0 = sigf(grA + grB), z0 = sigf(gzA + gzB);
        const float n0 = tanh_fast((gnA + gnB) + r0 * (hnA + hnB));
        h1n = (1.f - z0) * n0 + z0 * h1;
      }

      // chain B: layer 1, step t-1
      float grA1 = br1, gzA1 = bz1, gnA1 = bin1, hnA1 = bhn1;
      float grB1 = 0.f, gzB1 = 0.f, gnB1 = 0.f, hnB1 = 0.f;
#pragma unroll
      for (int r = 0; r < 4; ++r) {
        grA1 += wi1r[r] * rh1[r];     gzA1 += wi1z[r] * rh1[r];     gnA1 += wi1n[r] * rh1[r];
        grA1 += wh1r[r] * rh2[r];     gzA1 += wh1z[r] * rh2[r];     hnA1 += wh1n[r] * rh2[r];
        grB1 += wi1r[4+r] * rh1[4+r]; gzB1 += wi1z[4+r] * rh1[4+r]; gnB1 += wi1n[4+r] * rh1[4+r];
        grB1 += wh1r[4+r] * rh2[4+r]; gzB1 += wh1z[4+r] * rh2[4+r]; hnB1 += wh1n[4+r] * rh2[4+r];
      }
      float h2n;
      {
        const float r1 = sigf(grA1 + grB1), z1 = sigf(gzA1 + gzB1);
        const float n1 = tanh_fast((gnA1 + gnB1) + r1 * (hnA1 + hnB1));
        h2n = (1.f - z1) * n1 + z1 * h2;
      }

      h1 = h1n;
      h2 = (t == 0) ? 0.f : h2n;   // t=0 warm-up discard
      xcur = xnext;
    }

    // softmax over the 8 hidden units via rotations
    float rv[8]; rot8(rv, h2);
    float m = rv[0];
#pragma unroll
    for (int r = 1; r < 8; ++r) m = fmaxf(m, rv[r]);
    const float ej = __expf(h2 - m);
    float re[8]; rot8(re, ej);
    float sden = 0.f;
#pragma unroll
    for (int r = 0; r < 8; ++r) sden += re[r];
    if (!(tid & 8)) Omega[b * 8 + j] = __fdividef(ej, sden);
    return;
  }

  // ================= GEMM branch: Y1[sp][e] = Xm @ w1_e =================
  const int bid = blockIdx.x - 16;           // 0..191
  const int sp  = bid / 96;                  // 0..1
  const int rr0 = bid - sp * 96;
  const int e   = rr0 & 7;
  const int nt  = rr0 >> 3;                  // 0..11
  const int n0  = nt * 64;
  const int kt0 = sp * 8, kt1 = kt0 + 8;     // 16 K-tiles total (K padded 1024)

  const int r15 = lane & 15, hi4 = lane >> 4, r7 = lane & 7;

  const unsigned short* Abase = XmBf + (size_t)(wave * 64 + (lane >> 3)) * KA_N + (lane & 7) * 8;
  const int bn = lane;
  const int kq = wave;
  const bool nvalid = (n0 + bn) < HID_N;
  const float* Bbase = w1 + ((size_t)e * MOE_IN_N + kq * 16) * HID_N + (n0 + bn);

  f32x4 acc[4][4];
  const f32x4 zero4 = {0.f, 0.f, 0.f, 0.f};
#pragma unroll
  for (int mi = 0; mi < 4; ++mi)
#pragma unroll
    for (int ni = 0; ni < 4; ++ni) acc[mi][ni] = zero4;

  auto stage = [&](int bufi, int kt) {
    const unsigned short* ga = Abase + kt * 64;
#pragma unroll
    for (int it = 0; it < 8; ++it) {
      __builtin_amdgcn_global_load_lds(
          (AS1Q unsigned int*)(ga + (size_t)it * 8 * KA_N),
          (AS3Q unsigned int*)&sm.g.Al[bufi][wave * 64 + it * 8][0],
          16, 0, 0);
    }
    const int kbase = kt * 64 + kq * 16;
    const float* gb = Bbase + (size_t)kt * 64 * HID_N;
    float v[16];
#pragma unroll
    for (int jj = 0; jj < 16; ++jj)
      v[jj] = (nvalid && (kbase + jj) < MOE_IN_N) ? gb[(size_t)jj * HID_N] : 0.f;
    ushort8 p0, p1;
#pragma unroll
    for (int jj = 0; jj < 8; ++jj) { p0[jj] = f2bf(v[jj]); p1[jj] = f2bf(v[jj + 8]); }
    const int sl0 = ((kq * 2) ^ (bn & 7)) * 8;
    const int sl1 = ((kq * 2 + 1) ^ (bn & 7)) * 8;
    *(ushort8*)&sm.g.Bl[bufi][bn][sl0] = p0;
    *(ushort8*)&sm.g.Bl[bufi][bn][sl1] = p1;
  };

  auto compute = [&](int bufi) {
#pragma unroll
    for (int ki = 0; ki < 2; ++ki) {
      const int ch = ((ki * 4 + hi4) ^ r7) * 8;
      short8 af[4], bfv[4];
#pragma unroll
      for (int mi = 0; mi < 4; ++mi)
        af[mi] = *(const short8*)&sm.g.Al[bufi][wave * 64 + mi * 16 + r15][ch];
#pragma unroll
      for (int ni = 0; ni < 4; ++ni)
        bfv[ni] = *(const short8*)&sm.g.Bl[bufi][ni * 16 + r15][ch];
#pragma unroll
      for (int mi = 0; mi < 4; ++mi)
#pragma unroll
        for (int ni = 0; ni < 4; ++ni)
          acc[mi][ni] = __builtin_amdgcn_mfma_f32_16x16x32_bf16(af[mi], bfv[ni], acc[mi][ni], 0, 0, 0);
    }
  };

  stage(0, kt0);
  __syncthreads();
  int buf = 0;
  for (int kt = kt0; kt < kt1; ++kt) {
    if (kt + 1 < kt1) stage(buf ^ 1, kt + 1);
    compute(buf);
    __syncthreads();
    buf ^= 1;
  }

  float* Pp = Y1 + ((size_t)(sp * 8 + e) * 256) * PN + n0;
#pragma unroll
  for (int mi = 0; mi < 4; ++mi) {
    const int row = wave * 64 + mi * 16 + hi4 * 4;
#pragma unroll
    for (int ni = 0; ni < 4; ++ni) {
#pragma unroll
      for (int rq = 0; rq < 4; ++rq)
        Pp[(size_t)(row + rq) * PN + ni * 16 + r15] = acc[mi][ni][rq];
    }
  }
}

// ---------------------------------------------------------------------------
// reduce1: zero P (for gemm2 atomics), then
// a1 = elu( Sum_e Omega_e*(Y1[0][e]+Y1[1][e]) + Omega@b1 ) -> swizzled xt2.
// ---------------------------------------------------------------------------
__global__ __launch_bounds__(256)
void reduce1_mix(const float* __restrict__ Y1, const float* __restrict__ Omega,
                 const float* __restrict__ bias, unsigned short* __restrict__ xnext,
                 float* __restrict__ P)
{
  const int n = blockIdx.x * 256 + threadIdx.x;   // 0..767
  const int b = blockIdx.y;
  P[(size_t)b * PN + n] = 0.f;                    // zero for gemm2 atomics
  if (n >= HID_N) return;
  float om[8];
#pragma unroll
  for (int e = 0; e < 8; ++e) om[e] = Omega[b * 8 + e];
  float acc = 0.f, bs = 0.f;
#pragma unroll
  for (int e = 0; e < 8; ++e) {
    const float ye = Y1[((size_t)e * 256 + b) * PN + n]
                   + Y1[((size_t)(8 + e) * 256 + b) * PN + n];
    acc += om[e] * ye;
    bs  += om[e] * bias[(size_t)e * HID_N + n];
  }
  const float y = acc + bs;
  const float a = (y > 0.f) ? y : expm1f(y);      // ELU
  const int swz = (b & 7) << 3;
  unsigned short* row = xnext + (size_t)b * K2_N;
#pragma unroll
  for (int e = 0; e < 8; ++e)
    row[(e * HID_N + n) ^ swz] = f2bf(om[e] * a);
}

// ---------------------------------------------------------------------------
// Split-K GEMM, atomic reduction into L2-resident P[256][768] (pre-zeroed).
// ---------------------------------------------------------------------------
__global__ __launch_bounds__(256)
void gemm_splitk_atomic(const unsigned short* __restrict__ A,
                        const float* __restrict__ Bw,
                        float* __restrict__ P,
                        int K, int N)
{
  __shared__ unsigned short Al[2][256][64];
  __shared__ unsigned short Bl[2][64][64];

  const int tid = threadIdx.x;
  const int lane = tid & 63;
  const int wave = tid >> 6;
  const int nt = blockIdx.x, sp = blockIdx.y;
  const int n0 = nt * 64;
  const int KT = K >> 6;
  const int kt0 = (KT * sp) / SPLITK;
  const int kt1 = (KT * (sp + 1)) / SPLITK;

  const int r15 = lane & 15, hi4 = lane >> 4, r7 = lane & 7;

  const unsigned short* Abase = A + (size_t)(wave * 64 + (lane >> 3)) * K + (lane & 7) * 8;
  const int bn = lane;
  const int kq = wave;
  const bool nvalid = (n0 + bn) < N;
  const float* Bbase = Bw + (size_t)(kq * 16) * N + (n0 + bn);

  f32x4 acc[4][4];
  const f32x4 zero4 = {0.f, 0.f, 0.f, 0.f};
#pragma unroll
  for (int mi = 0; mi < 4; ++mi)
#pragma unroll
    for (int ni = 0; ni < 4; ++ni) acc[mi][ni] = zero4;

  auto stage = [&](int bufi, int kt) {
    const unsigned short* ga = Abase + kt * 64;
#pragma unroll
    for (int it = 0; it < 8; ++it) {
      __builtin_amdgcn_global_load_lds(
          (AS1Q unsigned int*)(ga + (size_t)it * 8 * K),
          (AS3Q unsigned int*)&Al[bufi][wave * 64 + it * 8][0],
          16, 0, 0);
    }
    const float* gb = Bbase + (size_t)kt * 64 * N;
    float v[16];
#pragma unroll
    for (int jj = 0; jj < 16; ++jj) v[jj] = nvalid ? gb[(size_t)jj * N] : 0.f;
    ushort8 p0, p1;
#pragma unroll
    for (int jj = 0; jj < 8; ++jj) { p0[jj] = f2bf(v[jj]); p1[jj] = f2bf(v[jj + 8]); }
    const int sl0 = ((kq * 2) ^ (bn & 7)) * 8;
    const int sl1 = ((kq * 2 + 1) ^ (bn & 7)) * 8;
    *(ushort8*)&Bl[bufi][bn][sl0] = p0;
    *(ushort8*)&Bl[bufi][bn][sl1] = p1;
  };

  auto compute = [&](int bufi) {
#pragma unroll
    for (int ki = 0; ki < 2; ++ki) {
      const int ch = ((ki * 4 + hi4) ^ r7) * 8;
      short8 af[4], bfv[4];
#pragma unroll
      for (int mi = 0; mi < 4; ++mi)
        af[mi] = *(const short8*)&Al[bufi][wave * 64 + mi * 16 + r15][ch];
#pragma unroll
      for (int ni = 0; ni < 4; ++ni)
        bfv[ni] = *(const short8*)&Bl[bufi][ni * 16 + r15][ch];
#pragma unroll
      for (int mi = 0; mi < 4; ++mi)
#pragma unroll
        for (int ni = 0; ni < 4; ++ni)
          acc[mi][ni] = __builtin_amdgcn_mfma_f32_16x16x32_bf16(af[mi], bfv[ni], acc[mi][ni], 0, 0, 0);
    }
  };

  stage(0, kt0);
  __syncthreads();
  int buf = 0;
  for (int kt = kt0; kt < kt1; ++kt) {
    if (kt + 1 < kt1) stage(buf ^ 1, kt + 1);
    compute(buf);
    __syncthreads();
    buf ^= 1;
  }

  float* Pp = P + n0;
#pragma unroll
  for (int mi = 0; mi < 4; ++mi) {
    const int row = wave * 64 + mi * 16 + hi4 * 4;
#pragma unroll
    for (int ni = 0; ni < 4; ++ni) {
#pragma unroll
      for (int rq = 0; rq < 4; ++rq)
        atomicAdd(&Pp[(size_t)(row + rq) * PN + ni * 16 + r15], acc[mi][ni][rq]);
    }
  }
}

// ---------------------------------------------------------------------------
// reduce_p: y = P[b][n] + Omega@bias; optional re-zero of P (for next gemm);
// then ELU+mix -> xnext, or final fp32 -> Yout.
// ---------------------------------------------------------------------------
__global__ __launch_bounds__(256)
void reduce_p(float* __restrict__ P, const float* __restrict__ Omega,
              const float* __restrict__ bias, unsigned short* __restrict__ xnext,
              float* __restrict__ Yout, int N, int zeroP)
{
  const int n = blockIdx.x * 256 + threadIdx.x;
  const int b = blockIdx.y;
  float v = 0.f;
  if (n < PN) {
    v = P[(size_t)b * PN + n];
    if (zeroP) P[(size_t)b * PN + n] = 0.f;
  }
  if (n >= N) return;
  float om[8];
#pragma unroll
  for (int e = 0; e < 8; ++e) om[e] = Omega[b * 8 + e];
  float bs = 0.f;
#pragma unroll
  for (int e = 0; e < 8; ++e) bs += om[e] * bias[(size_t)e * N + n];
  const float y = v + bs;
  if (Yout) { Yout[(size_t)b * N + n] = y; return; }
  const float a = (y > 0.f) ? y : expm1f(y);      // ELU
  const int swz = (b & 7) << 3;
  unsigned short* row = xnext + (size_t)b * K2_N;
#pragma unroll
  for (int e = 0; e < 8; ++e)
    row[(e * HID_N + n) ^ swz] = f2bf(om[e] * a);
}

// ---------------------------------------------------------------------------
extern "C" void kernel_launch(void* const* d_in, const int* in_sizes, int n_in,
                              void* d_out, int out_size, void* d_ws, size_t ws_size,
                              hipStream_t stream) {
  const float* X    = (const float*)d_in[0];
  const float* Wih0 = (const float*)d_in[1];
  const float* Whh0 = (const float*)d_in[2];
  const float* bih0 = (const float*)d_in[3];
  const float* bhh0 = (const float*)d_in[4];
  const float* Wih1 = (const float*)d_in[5];
  const float* Whh1 = (const float*)d_in[6];
  const float* bih1 = (const float*)d_in[7];
  const float* bhh1 = (const float*)d_in[8];
  const float* w1   = (const float*)d_in[9];
  const float* b1   = (const float*)d_in[10];
  const float* w2   = (const float*)d_in[11];
  const float* b2   = (const float*)d_in[12];
  const float* w3   = (const float*)d_in[13];
  const float* b3   = (const float*)d_in[14];

  char* ws = (char*)d_ws;
  float* Omega         = (float*)ws;                      // 8 KB
  unsigned short* XmBf = (unsigned short*)(ws + 8192);    // 524,288
  unsigned short* xt2  = (unsigned short*)(ws + 532480);  // 3,080,192
  unsigned short* xt3  = (unsigned short*)(ws + 3612672); // 3,080,192
  float* Y1            = (float*)(ws + 6692864);          // 12,582,912
  float* P             = (float*)(ws + 19275776);         // 786,432

  // Omega-free prep of bf16 Xm (swizzled, zero-padded to K=1024)
  xm_prep<<<dim3(4, 256), 256, 0, stream>>>(X, XmBf);

  // GRU (16 blocks) runs CONCURRENTLY with the expert GEMM (192 blocks)
  fused_gru_gemm1<<<208, 256, 0, stream>>>(X, Wih0, Whh0, bih0, bhh0,
                                           Wih1, Whh1, bih1, bhh1,
                                           XmBf, w1, Y1, Omega);

  // fold Omega + bias + ELU -> xt2 ; zero P for gemm2 atomics
  reduce1_mix<<<dim3(3, 256), 256, 0, stream>>>(Y1, Omega, b1, xt2, P);

  // layer 2: 256 x 6016 @ 6016 x 752  (atomic split-K into P)
  gemm_splitk_atomic<<<dim3(12, SPLITK), 256, 0, stream>>>(xt2, w2, P, K2_N, HID_N);
  reduce_p<<<dim3(3, 256), 256, 0, stream>>>(P, Omega, b2, xt3, nullptr, HID_N, 1);

  // layer 3: 256 x 6016 @ 6016 x 512  (atomic split-K into P)
  gemm_splitk_atomic<<<dim3(8, SPLITK), 256, 0, stream>>>(xt3, w3, P, K2_N, 512);
  reduce_p<<<dim3(2, 256), 256, 0, stream>>>(P, Omega, b3, nullptr, (float*)d_out, 512, 0);
}

// Round 11
// 80.865 us; speedup vs baseline: 1.6548x; 1.1467x over previous
//
#include <hip/hip_runtime.h>
#include <cstdint>
#include <cstddef>

typedef __attribute__((ext_vector_type(8))) short short8;
typedef __attribute__((ext_vector_type(8))) unsigned short ushort8;
typedef __attribute__((ext_vector_type(4))) float f32x4;

#define AS1Q const __attribute__((address_space(1)))
#define AS3Q __attribute__((address_space(3)))

constexpr int T_N = 60, IN_N = 520, MOE_RAW_N = 512, MOE_IN_N = 992;
constexpr int HID_N = 752, E_N = 8;
constexpr int K2_N = 6016;            // 8*752
constexpr int KA_N = 1024;            // padded Xm row length (992 -> 1024)
constexpr int SPLITK = 20;
constexpr int PN = 768;               // Y1 row pitch

static __device__ __forceinline__ unsigned short f2bf(float f) {
  unsigned int u = __float_as_uint(f);
  return (unsigned short)((u + 0x7fffu + ((u >> 16) & 1u)) >> 16);   // RNE
}
static __device__ __forceinline__ float sigf(float x) {
  return __fdividef(1.f, 1.f + __expf(-x));
}
static __device__ __forceinline__ float tanh_fast(float x) {
  return 2.f * __fdividef(1.f, 1.f + __expf(-2.f * x)) - 1.f;
}

// DPP row-rotate by R within the 16-lane row (pure VALU — no LDS pipe).
template<int R>
static __device__ __forceinline__ float rotf(float v) {
  return __int_as_float(__builtin_amdgcn_update_dpp(
      0, __float_as_int(v), 0x120 | R, 0xF, 0xF, true));
}
static __device__ __forceinline__ void rot8(float (&d)[8], float v) {
  d[0] = v;
  d[1] = rotf<1>(v); d[2] = rotf<2>(v); d[3] = rotf<3>(v);
  d[4] = rotf<4>(v); d[5] = rotf<5>(v); d[6] = rotf<6>(v); d[7] = rotf<7>(v);
}

// ---------------------------------------------------------------------------
// xm_prep: Xm_bf16[b][ (i ^ (b&7)<<3) ] = bf16(Xm[b,i]), rows padded to 1024.
// ---------------------------------------------------------------------------
__global__ __launch_bounds__(256)
void xm_prep(const float* __restrict__ X, unsigned short* __restrict__ XmBf)
{
  const int i = blockIdx.x * 256 + threadIdx.x;   // grid.x=4 -> 0..1023
  const int b = blockIdx.y;
  const float* Xb = X + (size_t)b * (T_N * IN_N);
  float v = 0.f;
  if (i < MOE_RAW_N) {
    v = Xb[(T_N - 1) * IN_N + i];
  } else if (i < MOE_IN_N) {
    const int q = i - MOE_RAW_N;
    v = Xb[(q >> 3) * IN_N + MOE_RAW_N + (q & 7)];
  }
  XmBf[(size_t)b * KA_N + (i ^ ((b & 7) << 3))] = f2bf(v);
}

// ---------------------------------------------------------------------------
// FUSED: GRU (blocks 0..15) + expert-separated layer-1 GEMM (blocks 16..207).
// ROUND-11 GRU FIX: the 96 loop-invariant weight floats now live in LDS
// (wl[12][8][8], 3 KB) and are read per-iteration via ds_read_b128. R3's
// VGPR_Count=76 < 96 live weights proved the register allocator was
// REMATERIALIZING weights from global memory every iteration (~70-100 L2
// loads/step == the stubborn ~1000cy/step that survived R4-R8). With weights
// in LDS, in-loop register pressure is ~60 (temps only) -> nothing to spill,
// and the LDS loads (loop-invariant addresses, independent) hide under the
// previous step's transcendental chain. Arithmetic identical to R6/R8.
// ---------------------------------------------------------------------------
__global__ __launch_bounds__(256, 1)
void fused_gru_gemm1(const float* __restrict__ X,
                     const float* __restrict__ Wih0, const float* __restrict__ Whh0,
                     const float* __restrict__ bih0, const float* __restrict__ bhh0,
                     const float* __restrict__ Wih1, const float* __restrict__ Whh1,
                     const float* __restrict__ bih1, const float* __restrict__ bhh1,
                     const unsigned short* __restrict__ XmBf,
                     const float* __restrict__ w1,
                     float* __restrict__ Y1, float* __restrict__ Omega)
{
  __shared__ union SM {
    struct { unsigned short Al[2][256][64]; unsigned short Bl[2][64][64]; } g; // 80 KB
    struct { float xl[T_N][256]; float wl[12][8][8]; } r;                      // 63 KB
  } sm;

  const int tid  = threadIdx.x;
  const int lane = tid & 63;
  const int wave = tid >> 6;

  if (blockIdx.x < 16) {
    // ================= GRU branch: 16 samples per block =================
    const int j = tid & 7;
    const int b = blockIdx.x * 16 + (tid >> 4);

    const float* xsrc = X + (size_t)b * (T_N * IN_N) + MOE_RAW_N + j;
#pragma unroll
    for (int t = 0; t < T_N; ++t) {
      __builtin_amdgcn_global_load_lds((AS1Q unsigned int*)(xsrc + t * IN_N),
                                       (AS3Q unsigned int*)&sm.r.xl[t][wave * 64], 4, 0, 0);
    }

    // probe DPP row_ror direction (uniform across lanes of same j)
    const int got = __builtin_amdgcn_update_dpp(0, j, 0x121, 0xF, 0xF, true);
    const bool plus = (got == ((j + 1) & 7));

    // ---- gather rotation-ordered weights into LDS: wl[mat*3+gate][j][r] ----
    // mats: 0..2 = Wih0 r/z/n, 3..5 = Whh0, 6..8 = Wih1, 9..11 = Whh1
    if (tid < 64) {
      const int fj = tid >> 3, fr = tid & 7;
      const int fi = plus ? ((fj + fr) & 7) : ((fj - fr) & 7);  // plus is j-dependent? no: recompute with fj
      // NOTE: 'plus' above used this thread's j == tid&7, but the fill needs fj = tid>>3.
      // Direction is a property of the HW, identical for all lanes; re-derive for fj:
      const int idx = plus ? ((fj + fr) & 7) : ((fj - fr) & 7);
      (void)fi;
      const float* Wm[4] = {Wih0, Whh0, Wih1, Whh1};
#pragma unroll
      for (int mat = 0; mat < 4; ++mat)
#pragma unroll
        for (int gg = 0; gg < 3; ++gg)
          sm.r.wl[mat * 3 + gg][fj][fr] = Wm[mat][(gg * 8 + fj) * 8 + idx];
    }

    const float br0 = bih0[j] + bhh0[j], bz0 = bih0[8 + j] + bhh0[8 + j];
    const float bin0 = bih0[16 + j],     bhn0 = bhh0[16 + j];
    const float br1 = bih1[j] + bhh1[j], bz1 = bih1[8 + j] + bhh1[8 + j];
    const float bin1 = bih1[16 + j],     bhn1 = bhh1[16 + j];

    __syncthreads();   // xl (vmcnt) + wl (lgkmcnt) ready

    float h1 = 0.f, h2 = 0.f;
    float xcur = sm.r.xl[0][tid];

    // 8 FMAs of one rotation-dot from LDS-resident weights
    auto dot8 = [&](int m, const float (&rv)[8], float& accA, float& accB) {
      const f32x4 w0 = *(const f32x4*)&sm.r.wl[m][j][0];
      const f32x4 w1v = *(const f32x4*)&sm.r.wl[m][j][4];
#pragma unroll
      for (int q = 0; q < 4; ++q) { accA += w0[q] * rv[q]; accB += w1v[q] * rv[4 + q]; }
    };

#pragma unroll 1
    for (int t = 0; t <= T_N; ++t) {   // 61 iterations (software pipeline)
      const float xnext = sm.r.xl[(t + 1 < T_N) ? t + 1 : T_N - 1][tid];

      float rx[8];  rot8(rx, xcur);
      float rh1[8]; rot8(rh1, h1);     // feeds BOTH chains
      float rh2[8]; rot8(rh2, h2);

      // chain A: layer 0, step t
      float grA = br0, gzA = bz0, gnA = bin0, hnA = bhn0;
      float grB = 0.f, gzB = 0.f, gnB = 0.f, hnB = 0.f;
      dot8(0, rx, grA, grB); dot8(1, rx, gzA, gzB); dot8(2, rx, gnA, gnB);
      dot8(3, rh1, grA, grB); dot8(4, rh1, gzA, gzB); dot8(5, rh1, hnA, hnB);
      float h1n;
      {
        const float r0 = sigf(grA + grB), z0 = sigf(gzA + gzB);
        const float n0 = tanh_fast((gnA + gnB) + r0 * (hnA + hnB));
        h1n = (1.f - z0) * n0 + z0 * h1;
      }

      // chain B: layer 1, step t-1
      float grA1 = br1, gzA1 = bz1, gnA1 = bin1, hnA1 = bhn1;
      float grB1 = 0.f, gzB1 = 0.f, gnB1 = 0.f, hnB1 = 0.f;
      dot8(6, rh1, grA1, grB1); dot8(7, rh1, gzA1, gzB1); dot8(8, rh1, gnA1, gnB1);
      dot8(9, rh2, grA1, grB1); dot8(10, rh2, gzA1, gzB1); dot8(11, rh2, hnA1, hnB1);
      float h2n;
      {
        const float r1 = sigf(grA1 + grB1), z1 = sigf(gzA1 + gzB1);
        const float n1 = tanh_fast((gnA1 + gnB1) + r1 * (hnA1 + hnB1));
        h2n = (1.f - z1) * n1 + z1 * h2;
      }

      h1 = h1n;
      h2 = (t == 0) ? 0.f : h2n;   // t=0 warm-up discard
      xcur = xnext;
    }

    // softmax over the 8 hidden units via rotations
    float rv[8]; rot8(rv, h2);
    float m = rv[0];
#pragma unroll
    for (int r = 1; r < 8; ++r) m = fmaxf(m, rv[r]);
    const float ej = __expf(h2 - m);
    float re[8]; rot8(re, ej);
    float sden = 0.f;
#pragma unroll
    for (int r = 0; r < 8; ++r) sden += re[r];
    if (!(tid & 8)) Omega[b * 8 + j] = __fdividef(ej, sden);
    return;
  }

  // ================= GEMM branch: Y1[sp][e] = Xm @ w1_e =================
  const int bid = blockIdx.x - 16;           // 0..191
  const int sp  = bid / 96;                  // 0..1
  const int rr0 = bid - sp * 96;
  const int e   = rr0 & 7;
  const int nt  = rr0 >> 3;                  // 0..11
  const int n0  = nt * 64;
  const int kt0 = sp * 8, kt1 = kt0 + 8;     // 16 K-tiles total (K padded 1024)

  const int r15 = lane & 15, hi4 = lane >> 4, r7 = lane & 7;

  const unsigned short* Abase = XmBf + (size_t)(wave * 64 + (lane >> 3)) * KA_N + (lane & 7) * 8;
  const int bn = lane;
  const int kq = wave;
  const bool nvalid = (n0 + bn) < HID_N;
  const float* Bbase = w1 + ((size_t)e * MOE_IN_N + kq * 16) * HID_N + (n0 + bn);

  f32x4 acc[4][4];
  const f32x4 zero4 = {0.f, 0.f, 0.f, 0.f};
#pragma unroll
  for (int mi = 0; mi < 4; ++mi)
#pragma unroll
    for (int ni = 0; ni < 4; ++ni) acc[mi][ni] = zero4;

  auto stage = [&](int bufi, int kt) {
    const unsigned short* ga = Abase + kt * 64;
#pragma unroll
    for (int it = 0; it < 8; ++it) {
      __builtin_amdgcn_global_load_lds(
          (AS1Q unsigned int*)(ga + (size_t)it * 8 * KA_N),
          (AS3Q unsigned int*)&sm.g.Al[bufi][wave * 64 + it * 8][0],
          16, 0, 0);
    }
    const int kbase = kt * 64 + kq * 16;
    const float* gb = Bbase + (size_t)kt * 64 * HID_N;
    float v[16];
#pragma unroll
    for (int jj = 0; jj < 16; ++jj)
      v[jj] = (nvalid && (kbase + jj) < MOE_IN_N) ? gb[(size_t)jj * HID_N] : 0.f;
    ushort8 p0, p1;
#pragma unroll
    for (int jj = 0; jj < 8; ++jj) { p0[jj] = f2bf(v[jj]); p1[jj] = f2bf(v[jj + 8]); }
    const int sl0 = ((kq * 2) ^ (bn & 7)) * 8;
    const int sl1 = ((kq * 2 + 1) ^ (bn & 7)) * 8;
    *(ushort8*)&sm.g.Bl[bufi][bn][sl0] = p0;
    *(ushort8*)&sm.g.Bl[bufi][bn][sl1] = p1;
  };

  auto compute = [&](int bufi) {
#pragma unroll
    for (int ki = 0; ki < 2; ++ki) {
      const int ch = ((ki * 4 + hi4) ^ r7) * 8;
      short8 af[4], bfv[4];
#pragma unroll
      for (int mi = 0; mi < 4; ++mi)
        af[mi] = *(const short8*)&sm.g.Al[bufi][wave * 64 + mi * 16 + r15][ch];
#pragma unroll
      for (int ni = 0; ni < 4; ++ni)
        bfv[ni] = *(const short8*)&sm.g.Bl[bufi][ni * 16 + r15][ch];
#pragma unroll
      for (int mi = 0; mi < 4; ++mi)
#pragma unroll
        for (int ni = 0; ni < 4; ++ni)
          acc[mi][ni] = __builtin_amdgcn_mfma_f32_16x16x32_bf16(af[mi], bfv[ni], acc[mi][ni], 0, 0, 0);
    }
  };

  stage(0, kt0);
  __syncthreads();
  int buf = 0;
  for (int kt = kt0; kt < kt1; ++kt) {
    if (kt + 1 < kt1) stage(buf ^ 1, kt + 1);
    compute(buf);
    __syncthreads();
    buf ^= 1;
  }

  float* Pp = Y1 + ((size_t)(sp * 8 + e) * 256) * PN + n0;
#pragma unroll
  for (int mi = 0; mi < 4; ++mi) {
    const int row = wave * 64 + mi * 16 + hi4 * 4;
#pragma unroll
    for (int ni = 0; ni < 4; ++ni) {
#pragma unroll
      for (int rq = 0; rq < 4; ++rq)
        Pp[(size_t)(row + rq) * PN + ni * 16 + r15] = acc[mi][ni][rq];
    }
  }
}

// ---------------------------------------------------------------------------
// reduce1: a1 = elu( Sum_e Omega_e*(Y1[0][e]+Y1[1][e]) + Omega@b1 ) -> xt2.
// ---------------------------------------------------------------------------
__global__ __launch_bounds__(256)
void reduce1_mix(const float* __restrict__ Y1, const float* __restrict__ Omega,
                 const float* __restrict__ bias, unsigned short* __restrict__ xnext)
{
  const int n = blockIdx.x * 256 + threadIdx.x;
  const int b = blockIdx.y;
  if (n >= HID_N) return;
  float om[8];
#pragma unroll
  for (int e = 0; e < 8; ++e) om[e] = Omega[b * 8 + e];
  float acc = 0.f, bs = 0.f;
#pragma unroll
  for (int e = 0; e < 8; ++e) {
    const float ye = Y1[((size_t)e * 256 + b) * PN + n]
                   + Y1[((size_t)(8 + e) * 256 + b) * PN + n];
    acc += om[e] * ye;
    bs  += om[e] * bias[(size_t)e * HID_N + n];
  }
  const float y = acc + bs;
  const float a = (y > 0.f) ? y : expm1f(y);      // ELU
  const int swz = (b & 7) << 3;
  unsigned short* row = xnext + (size_t)b * K2_N;
#pragma unroll
  for (int e = 0; e < 8; ++e)
    row[(e * HID_N + n) ^ swz] = f2bf(om[e] * a);
}

// ---------------------------------------------------------------------------
// Split-K GEMM (R8-proven): P[sp][256][NPAD] = A_slice @ B_slice (slab).
// ---------------------------------------------------------------------------
__global__ __launch_bounds__(256)
void gemm_splitk(const unsigned short* __restrict__ A,
                 const float* __restrict__ Bw,
                 float* __restrict__ P,
                 int K, int N, int NPAD)
{
  __shared__ unsigned short Al[2][256][64];
  __shared__ unsigned short Bl[2][64][64];

  const int tid = threadIdx.x;
  const int lane = tid & 63;
  const int wave = tid >> 6;
  const int nt = blockIdx.x, sp = blockIdx.y;
  const int n0 = nt * 64;
  const int KT = K >> 6;
  const int kt0 = (KT * sp) / SPLITK;
  const int kt1 = (KT * (sp + 1)) / SPLITK;

  const int r15 = lane & 15, hi4 = lane >> 4, r7 = lane & 7;

  const unsigned short* Abase = A + (size_t)(wave * 64 + (lane >> 3)) * K + (lane & 7) * 8;
  const int bn = lane;
  const int kq = wave;
  const bool nvalid = (n0 + bn) < N;
  const float* Bbase = Bw + (size_t)(kq * 16) * N + (n0 + bn);

  f32x4 acc[4][4];
  const f32x4 zero4 = {0.f, 0.f, 0.f, 0.f};
#pragma unroll
  for (int mi = 0; mi < 4; ++mi)
#pragma unroll
    for (int ni = 0; ni < 4; ++ni) acc[mi][ni] = zero4;

  auto stage = [&](int bufi, int kt) {
    const unsigned short* ga = Abase + kt * 64;
#pragma unroll
    for (int it = 0; it < 8; ++it) {
      __builtin_amdgcn_global_load_lds(
          (AS1Q unsigned int*)(ga + (size_t)it * 8 * K),
          (AS3Q unsigned int*)&Al[bufi][wave * 64 + it * 8][0],
          16, 0, 0);
    }
    const float* gb = Bbase + (size_t)kt * 64 * N;
    float v[16];
#pragma unroll
    for (int jj = 0; jj < 16; ++jj) v[jj] = nvalid ? gb[(size_t)jj * N] : 0.f;
    ushort8 p0, p1;
#pragma unroll
    for (int jj = 0; jj < 8; ++jj) { p0[jj] = f2bf(v[jj]); p1[jj] = f2bf(v[jj + 8]); }
    const int sl0 = ((kq * 2) ^ (bn & 7)) * 8;
    const int sl1 = ((kq * 2 + 1) ^ (bn & 7)) * 8;
    *(ushort8*)&Bl[bufi][bn][sl0] = p0;
    *(ushort8*)&Bl[bufi][bn][sl1] = p1;
  };

  auto compute = [&](int bufi) {
#pragma unroll
    for (int ki = 0; ki < 2; ++ki) {
      const int ch = ((ki * 4 + hi4) ^ r7) * 8;
      short8 af[4], bfv[4];
#pragma unroll
      for (int mi = 0; mi < 4; ++mi)
        af[mi] = *(const short8*)&Al[bufi][wave * 64 + mi * 16 + r15][ch];
#pragma unroll
      for (int ni = 0; ni < 4; ++ni)
        bfv[ni] = *(const short8*)&Bl[bufi][ni * 16 + r15][ch];
#pragma unroll
      for (int mi = 0; mi < 4; ++mi)
#pragma unroll
        for (int ni = 0; ni < 4; ++ni)
          acc[mi][ni] = __builtin_amdgcn_mfma_f32_16x16x32_bf16(af[mi], bfv[ni], acc[mi][ni], 0, 0, 0);
    }
  };

  stage(0, kt0);
  __syncthreads();
  int buf = 0;
  for (int kt = kt0; kt < kt1; ++kt) {
    if (kt + 1 < kt1) stage(buf ^ 1, kt + 1);
    compute(buf);
    __syncthreads();
    buf ^= 1;
  }

  float* Pp = P + (size_t)sp * 256 * NPAD + n0;
#pragma unroll
  for (int mi = 0; mi < 4; ++mi) {
    const int row = wave * 64 + mi * 16 + hi4 * 4;
#pragma unroll
    for (int ni = 0; ni < 4; ++ni) {
#pragma unroll
      for (int rq = 0; rq < 4; ++rq)
        Pp[(size_t)(row + rq) * NPAD + ni * 16 + r15] = acc[mi][ni][rq];
    }
  }
}

// ---------------------------------------------------------------------------
// Reduce split-K partials + Omega-blended bias; ELU+mix -> xnext, or final out.
// ---------------------------------------------------------------------------
__global__ __launch_bounds__(256)
void reduce_mix_kernel(const float* __restrict__ P, const float* __restrict__ Omega,
                       const float* __restrict__ bias, unsigned short* __restrict__ xnext,
                       float* __restrict__ Yout, int N, int NPAD)
{
  const int n = blockIdx.x * 256 + threadIdx.x;
  const int b = blockIdx.y;
  if (n >= N) return;
  float acc = 0.f;
#pragma unroll 4
  for (int s = 0; s < SPLITK; ++s) acc += P[((size_t)s * 256 + b) * NPAD + n];
  float om[8];
#pragma unroll
  for (int e = 0; e < 8; ++e) om[e] = Omega[b * 8 + e];
  float bs = 0.f;
#pragma unroll
  for (int e = 0; e < 8; ++e) bs += om[e] * bias[(size_t)e * N + n];
  float y = acc + bs;
  if (Yout) { Yout[(size_t)b * N + n] = y; return; }
  float a = (y > 0.f) ? y : expm1f(y);            // ELU
  const int swz = (b & 7) << 3;
  unsigned short* row = xnext + (size_t)b * K2_N;
#pragma unroll
  for (int e = 0; e < 8; ++e)
    row[(e * HID_N + n) ^ swz] = f2bf(om[e] * a);
}

// ---------------------------------------------------------------------------
extern "C" void kernel_launch(void* const* d_in, const int* in_sizes, int n_in,
                              void* d_out, int out_size, void* d_ws, size_t ws_size,
                              hipStream_t stream) {
  const float* X    = (const float*)d_in[0];
  const float* Wih0 = (const float*)d_in[1];
  const float* Whh0 = (const float*)d_in[2];
  const float* bih0 = (const float*)d_in[3];
  const float* bhh0 = (const float*)d_in[4];
  const float* Wih1 = (const float*)d_in[5];
  const float* Whh1 = (const float*)d_in[6];
  const float* bih1 = (const float*)d_in[7];
  const float* bhh1 = (const float*)d_in[8];
  const float* w1   = (const float*)d_in[9];
  const float* b1   = (const float*)d_in[10];
  const float* w2   = (const float*)d_in[11];
  const float* b2   = (const float*)d_in[12];
  const float* w3   = (const float*)d_in[13];
  const float* b3   = (const float*)d_in[14];

  char* ws = (char*)d_ws;
  float* Omega         = (float*)ws;                      // 8 KB
  unsigned short* XmBf = (unsigned short*)(ws + 8192);    // 524,288
  unsigned short* xt2  = (unsigned short*)(ws + 532480);  // 3,080,192
  unsigned short* xt3  = (unsigned short*)(ws + 3612672); // 3,080,192
  float* Y1            = (float*)(ws + 6692864);          // 12,582,912
  float* P             = (float*)(ws + 19275776);         // 15,728,640

  // Omega-free prep of bf16 Xm (swizzled, zero-padded to K=1024)
  xm_prep<<<dim3(4, 256), 256, 0, stream>>>(X, XmBf);

  // GRU (16 blocks) runs CONCURRENTLY with the expert GEMM (192 blocks)
  fused_gru_gemm1<<<208, 256, 0, stream>>>(X, Wih0, Whh0, bih0, bhh0,
                                           Wih1, Whh1, bih1, bhh1,
                                           XmBf, w1, Y1, Omega);

  // fold Omega + bias + ELU -> xt2
  reduce1_mix<<<dim3(3, 256), 256, 0, stream>>>(Y1, Omega, b1, xt2);

  // layer 2: 256 x 6016 @ 6016 x 752  (slab split-K, R8-proven)
  gemm_splitk<<<dim3(12, SPLITK), 256, 0, stream>>>(xt2, w2, P, K2_N, HID_N, 768);
  reduce_mix_kernel<<<dim3(3, 256), 256, 0, stream>>>(P, Omega, b2, xt3, nullptr, HID_N, 768);

  // layer 3: 256 x 6016 @ 6016 x 512  (slab split-K)
  gemm_splitk<<<dim3(8, SPLITK), 256, 0, stream>>>(xt3, w3, P, K2_N, 512, 512);
  reduce_mix_kernel<<<dim3(2, 256), 256, 0, stream>>>(P, Omega, b3, nullptr, (float*)d_out, 512, 512);
}